// Round 17
// baseline (747.506 us; speedup 1.0000x reference)
//
#include <hip/hip_runtime.h>

#define HDIM 64

typedef _Float16 h2  __attribute__((ext_vector_type(2)));   // dot2 operand type
typedef __fp16   fp2 __attribute__((ext_vector_type(2)));   // cvt_pkrtz result type

#if defined(__has_builtin)
# if __has_builtin(__builtin_amdgcn_fdot2)
#  define FDOT2(a, b, c) __builtin_amdgcn_fdot2((a), (b), (c), false)
# endif
#endif
#ifndef FDOT2
__device__ __forceinline__ float fdot2_asm(h2 a, h2 b, float c) {
    float d;
    asm("v_dot2_f32_f16 %0, %1, %2, %3" : "=v"(d) : "v"(a), "v"(b), "v"(c));
    return d;
}
# define FDOT2(a, b, c) fdot2_asm((a), (b), (c))
#endif

__device__ __forceinline__ float fast_sigmoid(float v) {
    return __builtin_amdgcn_rcpf(1.0f + __builtin_amdgcn_exp2f(-1.442695041f * v));
}

__device__ __forceinline__ float fast_tanh(float v) {
    return 1.0f - 2.0f * __builtin_amdgcn_rcpf(1.0f + __builtin_amdgcn_exp2f(2.885390082f * v));
}

// ONE WAVE per TWO batch elements (256 blocks x 64 threads), no barriers, no
// cross-lane reduce. Lane l owns all 4 gate rows of unit l (full K=64 dots);
// recurrent weights are f16-packed in 128 VGPRs and SHARED by both elements.
// The two independent recurrences interleave inside the wave: each chain's
// serial latencies (LDS write->read turnaround, exp/rcp chains, read latency)
// hide under the other's dot2 issue — r16 measured 1195 cy/step with ~650 of
// issue+latency, i.e. ~45% stall, with nothing else on the SIMD to fill it.
// h hand-off: ds_write_b16 -> 8 broadcast b128 reads next step (in-order DS
// within the wave, validated r7/r16). x: per-step global prefetch (no
// barriers -> no vmcnt drain). w_ih is f16-packed too (dot2), saving 8 regs.
__global__ __launch_bounds__(64)
__attribute__((amdgpu_waves_per_eu(1, 1)))
void bilstm_kernel(const float* __restrict__ x,
                   const float* __restrict__ w_ih_f,
                   const float* __restrict__ w_hh_f,
                   const float* __restrict__ b_ih_f,
                   const float* __restrict__ b_hh_f,
                   const float* __restrict__ w_ih_b,
                   const float* __restrict__ b_ih_b,
                   const float* __restrict__ b_hh_b,
                   const float* __restrict__ w_fc,
                   const float* __restrict__ b_fc,
                   float* __restrict__ out,
                   int T)
{
    const int b0 = 2 * blockIdx.x;
    const int b1 = b0 + 1;
    const int l  = threadIdx.x;    // unit index; owns rows {l, 64+l, 128+l, 192+l}

    __shared__ __align__(16) _Float16 hlds0[HDIM];
    __shared__ __align__(16) _Float16 hlds1[HDIM];

    // ---- pack 4x64 recurrent weights into 128 h2 regs (shared by both elems) ----
    unsigned wu[128];              // [g*32 + q2] = packed {w[2q2], w[2q2+1]}
    #pragma unroll
    for (int g = 0; g < 4; ++g) {
        const float* row = w_hh_f + (size_t)((g << 6) | l) * HDIM;
        #pragma unroll
        for (int q = 0; q < 16; ++q) {
            float4 v = *(const float4*)(row + 4 * q);
            fp2 p0 = __builtin_amdgcn_cvt_pkrtz(v.x, v.y);
            fp2 p1 = __builtin_amdgcn_cvt_pkrtz(v.z, v.w);
            wu[(g << 5) + 2 * q + 0] = __builtin_bit_cast(unsigned, p0);
            wu[(g << 5) + 2 * q + 1] = __builtin_bit_cast(unsigned, p1);
        }
    }
    #pragma unroll
    for (int q = 0; q < 16; ++q) {
        asm volatile("" : "+v"(wu[8*q+0]), "+v"(wu[8*q+1]),
                          "+v"(wu[8*q+2]), "+v"(wu[8*q+3]),
                          "+v"(wu[8*q+4]), "+v"(wu[8*q+5]),
                          "+v"(wu[8*q+6]), "+v"(wu[8*q+7]));
    }

    // ---- f16-packed input weights (8 regs) + fused bias ----
    unsigned wxu[8];               // [g*2 + k] = packed {w_ih[4g..]}
    float    bz[4];
    #pragma unroll
    for (int g = 0; g < 4; ++g) {
        const int r = (g << 6) | l;
        float4 v = *(const float4*)(w_ih_f + (size_t)r * 4);
        fp2 p0 = __builtin_amdgcn_cvt_pkrtz(v.x, v.y);
        fp2 p1 = __builtin_amdgcn_cvt_pkrtz(v.z, v.w);
        wxu[2*g + 0] = __builtin_bit_cast(unsigned, p0);
        wxu[2*g + 1] = __builtin_bit_cast(unsigned, p1);
        bz[g] = b_ih_f[r] + b_hh_f[r];
    }
    asm volatile("" : "+v"(wxu[0]), "+v"(wxu[1]), "+v"(wxu[2]), "+v"(wxu[3]),
                      "+v"(wxu[4]), "+v"(wxu[5]), "+v"(wxu[6]), "+v"(wxu[7]));
    asm volatile("" : "+v"(bz[0]), "+v"(bz[1]), "+v"(bz[2]), "+v"(bz[3]));

    hlds0[l] = (_Float16)0.0f;
    hlds1[l] = (_Float16)0.0f;

    const float* xb0 = x + (size_t)b0 * T * 4;
    const float* xb1 = x + (size_t)b1 * T * 4;
    float4 xc0 = *(const float4*)xb0;
    float4 xc1 = *(const float4*)xb1;
    float c0 = 0.0f, h0 = 0.0f, c1 = 0.0f, h1 = 0.0f;

    #define W2(g, qq) __builtin_bit_cast(h2, wu[((g) << 5) + (qq)])
    #define WX2(k)    __builtin_bit_cast(h2, wxu[k])
    #define H2(u)     __builtin_bit_cast(h2, (u))

    for (int t = 0; t < T; ++t) {
        const int tn = (t + 1 < T) ? t + 1 : T - 1;
        float4 xn0 = *(const float4*)(xb0 + 4 * tn);   // stays in flight
        float4 xn1 = *(const float4*)(xb1 + 4 * tn);

        // 16 accumulator chains: [elem][gate] x {A,B}, 16 dot2 deep each
        float accA[2][4], accB[2][4];
        #pragma unroll
        for (int g = 0; g < 4; ++g) {
            accA[0][g] = bz[g]; accB[0][g] = 0.0f;
            accA[1][g] = bz[g]; accB[1][g] = 0.0f;
        }

        const uint4* hp0 = (const uint4*)hlds0;
        const uint4* hp1 = (const uint4*)hlds1;
        #pragma unroll
        for (int q = 0; q < 8; ++q) {
            const uint4 v0 = hp0[q];       // broadcast b128 = 8 halves
            const uint4 v1 = hp1[q];
            #pragma unroll
            for (int g = 0; g < 4; ++g) {
                accA[0][g] = FDOT2(W2(g, 4*q+0), H2(v0.x), accA[0][g]);
                accB[0][g] = FDOT2(W2(g, 4*q+1), H2(v0.y), accB[0][g]);
                accA[0][g] = FDOT2(W2(g, 4*q+2), H2(v0.z), accA[0][g]);
                accB[0][g] = FDOT2(W2(g, 4*q+3), H2(v0.w), accB[0][g]);
                accA[1][g] = FDOT2(W2(g, 4*q+0), H2(v1.x), accA[1][g]);
                accB[1][g] = FDOT2(W2(g, 4*q+1), H2(v1.y), accB[1][g]);
                accA[1][g] = FDOT2(W2(g, 4*q+2), H2(v1.z), accA[1][g]);
                accB[1][g] = FDOT2(W2(g, 4*q+3), H2(v1.w), accB[1][g]);
            }
        }

        // fold x (f16-packed dot2)
        const unsigned x01_0 = __builtin_bit_cast(unsigned, __builtin_amdgcn_cvt_pkrtz(xc0.x, xc0.y));
        const unsigned x23_0 = __builtin_bit_cast(unsigned, __builtin_amdgcn_cvt_pkrtz(xc0.z, xc0.w));
        const unsigned x01_1 = __builtin_bit_cast(unsigned, __builtin_amdgcn_cvt_pkrtz(xc1.x, xc1.y));
        const unsigned x23_1 = __builtin_bit_cast(unsigned, __builtin_amdgcn_cvt_pkrtz(xc1.z, xc1.w));

        float pre[2][4];
        #pragma unroll
        for (int g = 0; g < 4; ++g) {
            float t0 = accA[0][g] + accB[0][g];
            t0 = FDOT2(WX2(2*g + 0), H2(x01_0), t0);
            t0 = FDOT2(WX2(2*g + 1), H2(x23_0), t0);
            pre[0][g] = t0;
            float t1 = accA[1][g] + accB[1][g];
            t1 = FDOT2(WX2(2*g + 0), H2(x01_1), t1);
            t1 = FDOT2(WX2(2*g + 1), H2(x23_1), t1);
            pre[1][g] = t1;
        }

        // activations + cell, both elements (independent chains interleave)
        {
            const float gi = fast_sigmoid(pre[0][0]);
            const float gf = fast_sigmoid(pre[0][1]);
            const float gg = fast_tanh(pre[0][2]);
            const float go = fast_sigmoid(pre[0][3]);
            c0 = gf * c0 + gi * gg;
            h0 = go * fast_tanh(c0);
        }
        {
            const float gi = fast_sigmoid(pre[1][0]);
            const float gf = fast_sigmoid(pre[1][1]);
            const float gg = fast_tanh(pre[1][2]);
            const float go = fast_sigmoid(pre[1][3]);
            c1 = gf * c1 + gi * gg;
            h1 = go * fast_tanh(c1);
        }

        hlds0[l] = (_Float16)h0;             // next step's reads see these (in-order DS)
        hlds1[l] = (_Float16)h1;
        asm volatile("" ::: "memory");
        xc0 = xn0;
        xc1 = xn1;
    }

    #undef W2
    #undef WX2
    #undef H2

    // ---- epilogue: backward cell + fc + sigmoid for both elements ----
    // (w_hh_b never multiplies nonzero state; xc0/xc1 == x[:, T-1])
    #pragma unroll
    for (int e = 0; e < 2; ++e) {
        const float4 xl = e ? xc1 : xc0;
        const float  hf = e ? h1 : h0;
        float gb[4];
        #pragma unroll
        for (int g = 0; g < 4; ++g) {
            const int r = (g << 6) | l;
            float4 wb = *(const float4*)(w_ih_b + (size_t)r * 4);
            gb[g] = b_ih_b[r] + b_hh_b[r]
                  + wb.x * xl.x + wb.y * xl.y + wb.z * xl.z + wb.w * xl.w;
        }
        const float ib  = fast_sigmoid(gb[0]);
        const float ggb = fast_tanh(gb[2]);
        const float ob  = fast_sigmoid(gb[3]);
        const float cb  = ib * ggb;
        const float hbk = ob * fast_tanh(cb);

        float p = w_fc[l] * hf + w_fc[HDIM + l] * hbk;
        #pragma unroll
        for (int off = 32; off; off >>= 1) p += __shfl_xor(p, off);

        if (l == 0) out[e ? b1 : b0] = fast_sigmoid(p + b_fc[0]);
    }
}

extern "C" void kernel_launch(void* const* d_in, const int* in_sizes, int n_in,
                              void* d_out, int out_size, void* d_ws, size_t ws_size,
                              hipStream_t stream) {
    const float* x      = (const float*)d_in[0];
    const float* w_ih_f = (const float*)d_in[1];
    const float* w_hh_f = (const float*)d_in[2];
    const float* b_ih_f = (const float*)d_in[3];
    const float* b_hh_f = (const float*)d_in[4];
    const float* w_ih_b = (const float*)d_in[5];
    // d_in[6] = w_hh_b — unused (backward cell starts from zero state)
    const float* b_ih_b = (const float*)d_in[7];
    const float* b_hh_b = (const float*)d_in[8];
    const float* w_fc   = (const float*)d_in[9];
    const float* b_fc   = (const float*)d_in[10];
    float* out = (float*)d_out;

    const int B = out_size;                 // 512
    const int T = in_sizes[0] / (B * 4);    // 1000

    bilstm_kernel<<<dim3(B / 2), dim3(64), 0, stream>>>(
        x, w_ih_f, w_hh_f, b_ih_f, b_hh_f,
        w_ih_b, b_ih_b, b_hh_b, w_fc, b_fc, out, T);
}

// Round 18
// 447.043 us; speedup vs baseline: 1.6721x; 1.6721x over previous
//
#include <hip/hip_runtime.h>

#define HDIM 64

typedef _Float16 h2  __attribute__((ext_vector_type(2)));   // dot2 operand type
typedef __fp16   fp2 __attribute__((ext_vector_type(2)));   // cvt_pkrtz result type

#if defined(__has_builtin)
# if __has_builtin(__builtin_amdgcn_fdot2)
#  define FDOT2(a, b, c) __builtin_amdgcn_fdot2((a), (b), (c), false)
# endif
#endif
#ifndef FDOT2
__device__ __forceinline__ float fdot2_asm(h2 a, h2 b, float c) {
    float d;
    asm("v_dot2_f32_f16 %0, %1, %2, %3" : "=v"(d) : "v"(a), "v"(b), "v"(c));
    return d;
}
# define FDOT2(a, b, c) fdot2_asm((a), (b), (c))
#endif

__device__ __forceinline__ float fast_sigmoid(float v) {
    return __builtin_amdgcn_rcpf(1.0f + __builtin_amdgcn_exp2f(-1.442695041f * v));
}

__device__ __forceinline__ float fast_tanh(float v) {
    return 1.0f - 2.0f * __builtin_amdgcn_rcpf(1.0f + __builtin_amdgcn_exp2f(2.885390082f * v));
}

// ONE WAVE per batch element (512 blocks x 64 threads = 2 waves/CU), no
// barriers, no cross-lane reduce. Lane l owns all 4 gate rows of unit l with
// full K=64 dots; weights f16-packed in 128 regs (v_dot2_f32_f16, f32 accum).
// Round-18 change vs r16: the weight pins are ALSO inside the t-loop. r16's
// VGPR_Count=132 (< 128 wu + working set) implies the allocator gave wu an
// AGPR home and paid v_accvgpr_read per use (~128 VALU ops = ~256 cy/step).
// An in-loop "+v" pin is free if wu is VGPR-resident and forces the VGPR
// home otherwise (AGPR home would cost 2 copies per reg per iteration —
// strictly worse for the allocator).
// h hand-off: ds_write_b16 -> 8 broadcast b128 reads next step (in-order DS
// within the wave, validated r7/r16). x: per-step global prefetch.
__global__ __launch_bounds__(64)
__attribute__((amdgpu_waves_per_eu(1, 1)))
void bilstm_kernel(const float* __restrict__ x,
                   const float* __restrict__ w_ih_f,
                   const float* __restrict__ w_hh_f,
                   const float* __restrict__ b_ih_f,
                   const float* __restrict__ b_hh_f,
                   const float* __restrict__ w_ih_b,
                   const float* __restrict__ b_ih_b,
                   const float* __restrict__ b_hh_b,
                   const float* __restrict__ w_fc,
                   const float* __restrict__ b_fc,
                   float* __restrict__ out,
                   int T)
{
    const int b = blockIdx.x;
    const int l = threadIdx.x;     // unit index; owns rows {l, 64+l, 128+l, 192+l}

    __shared__ __align__(16) _Float16 hlds[HDIM];

    // ---- pack 4x64 recurrent weights into 128 h2 regs (stored as uint) ----
    unsigned wu[128];              // [g*32 + q2] = packed {w[2q2], w[2q2+1]}
    #pragma unroll
    for (int g = 0; g < 4; ++g) {
        const float* row = w_hh_f + (size_t)((g << 6) | l) * HDIM;
        #pragma unroll
        for (int q = 0; q < 16; ++q) {
            float4 v = *(const float4*)(row + 4 * q);
            fp2 p0 = __builtin_amdgcn_cvt_pkrtz(v.x, v.y);
            fp2 p1 = __builtin_amdgcn_cvt_pkrtz(v.z, v.w);
            wu[(g << 5) + 2 * q + 0] = __builtin_bit_cast(unsigned, p0);
            wu[(g << 5) + 2 * q + 1] = __builtin_bit_cast(unsigned, p1);
        }
    }

    #define PIN_WU()                                                        \
        _Pragma("unroll")                                                   \
        for (int qq = 0; qq < 16; ++qq) {                                   \
            asm volatile("" : "+v"(wu[8*qq+0]), "+v"(wu[8*qq+1]),           \
                              "+v"(wu[8*qq+2]), "+v"(wu[8*qq+3]),           \
                              "+v"(wu[8*qq+4]), "+v"(wu[8*qq+5]),           \
                              "+v"(wu[8*qq+6]), "+v"(wu[8*qq+7]));          \
        }

    PIN_WU()

    float4 wx[4];
    float  bz[4];
    #pragma unroll
    for (int g = 0; g < 4; ++g) {
        const int r = (g << 6) | l;
        wx[g] = *(const float4*)(w_ih_f + (size_t)r * 4);
        bz[g] = b_ih_f[r] + b_hh_f[r];
        asm volatile("" : "+v"(wx[g].x), "+v"(wx[g].y), "+v"(wx[g].z),
                          "+v"(wx[g].w), "+v"(bz[g]));
    }

    hlds[l] = (_Float16)0.0f;      // in-order DS: visible to step-0 reads

    const float* xb = x + (size_t)b * T * 4;
    float4 xcur = *(const float4*)(xb);
    float c = 0.0f, h = 0.0f;

    #define W2(g, qq) __builtin_bit_cast(h2, wu[((g) << 5) + (qq)])
    #define H2(u)     __builtin_bit_cast(h2, (u))

    for (int t = 0; t < T; ++t) {
        PIN_WU()   // in-loop: free if VGPR-resident; forces VGPR home otherwise

        const int tn = (t + 1 < T) ? t + 1 : T - 1;
        float4 xnext = *(const float4*)(xb + 4 * tn);   // no barrier -> stays in flight

        // 8 accumulator chains (2 per gate), v_dot2_f32_f16, 16 deep each
        float aA0 = bz[0], aB0 = 0.0f;
        float aA1 = bz[1], aB1 = 0.0f;
        float aA2 = bz[2], aB2 = 0.0f;
        float aA3 = bz[3], aB3 = 0.0f;

        const uint4* hp = (const uint4*)hlds;
        #pragma unroll
        for (int q = 0; q < 8; ++q) {
            const uint4 hv = hp[q];        // broadcast b128 = 8 halves
            aA0 = FDOT2(W2(0, 4*q+0), H2(hv.x), aA0);
            aB0 = FDOT2(W2(0, 4*q+1), H2(hv.y), aB0);
            aA0 = FDOT2(W2(0, 4*q+2), H2(hv.z), aA0);
            aB0 = FDOT2(W2(0, 4*q+3), H2(hv.w), aB0);
            aA1 = FDOT2(W2(1, 4*q+0), H2(hv.x), aA1);
            aB1 = FDOT2(W2(1, 4*q+1), H2(hv.y), aB1);
            aA1 = FDOT2(W2(1, 4*q+2), H2(hv.z), aA1);
            aB1 = FDOT2(W2(1, 4*q+3), H2(hv.w), aB1);
            aA2 = FDOT2(W2(2, 4*q+0), H2(hv.x), aA2);
            aB2 = FDOT2(W2(2, 4*q+1), H2(hv.y), aB2);
            aA2 = FDOT2(W2(2, 4*q+2), H2(hv.z), aA2);
            aB2 = FDOT2(W2(2, 4*q+3), H2(hv.w), aB2);
            aA3 = FDOT2(W2(3, 4*q+0), H2(hv.x), aA3);
            aB3 = FDOT2(W2(3, 4*q+1), H2(hv.y), aB3);
            aA3 = FDOT2(W2(3, 4*q+2), H2(hv.z), aA3);
            aB3 = FDOT2(W2(3, 4*q+3), H2(hv.w), aB3);
        }

        float A0 = aA0 + aB0 + (wx[0].x * xcur.x + wx[0].y * xcur.y
                              + wx[0].z * xcur.z + wx[0].w * xcur.w);
        float A1 = aA1 + aB1 + (wx[1].x * xcur.x + wx[1].y * xcur.y
                              + wx[1].z * xcur.z + wx[1].w * xcur.w);
        float A2 = aA2 + aB2 + (wx[2].x * xcur.x + wx[2].y * xcur.y
                              + wx[2].z * xcur.z + wx[2].w * xcur.w);
        float A3 = aA3 + aB3 + (wx[3].x * xcur.x + wx[3].y * xcur.y
                              + wx[3].z * xcur.z + wx[3].w * xcur.w);

        const float gi = fast_sigmoid(A0);
        const float gf = fast_sigmoid(A1);
        const float gg = fast_tanh(A2);
        const float go = fast_sigmoid(A3);
        c = gf * c + gi * gg;
        h = go * fast_tanh(c);

        hlds[l] = (_Float16)h;               // ds_write_b16; next step's reads see it
        asm volatile("" ::: "memory");       // keep program order around LDS
        xcur = xnext;
    }

    #undef W2
    #undef H2
    #undef PIN_WU

    // ---- backward-direction cell: single step from zero state at x[:, T-1] ----
    // (w_hh_b never multiplies nonzero state; xcur == x[:, T-1] here)
    float gb[4];
    #pragma unroll
    for (int g = 0; g < 4; ++g) {
        const int r = (g << 6) | l;
        float4 wb = *(const float4*)(w_ih_b + (size_t)r * 4);
        gb[g] = b_ih_b[r] + b_hh_b[r]
              + wb.x * xcur.x + wb.y * xcur.y + wb.z * xcur.z + wb.w * xcur.w;
    }
    const float ib  = fast_sigmoid(gb[0]);
    const float ggb = fast_tanh(gb[2]);
    const float ob  = fast_sigmoid(gb[3]);
    const float cb  = ib * ggb;
    const float hb  = ob * fast_tanh(cb);

    // ---- fc + sigmoid ----
    float p = w_fc[l] * h + w_fc[HDIM + l] * hb;
    #pragma unroll
    for (int off = 32; off; off >>= 1) p += __shfl_xor(p, off);

    if (l == 0) out[b] = fast_sigmoid(p + b_fc[0]);
}

extern "C" void kernel_launch(void* const* d_in, const int* in_sizes, int n_in,
                              void* d_out, int out_size, void* d_ws, size_t ws_size,
                              hipStream_t stream) {
    const float* x      = (const float*)d_in[0];
    const float* w_ih_f = (const float*)d_in[1];
    const float* w_hh_f = (const float*)d_in[2];
    const float* b_ih_f = (const float*)d_in[3];
    const float* b_hh_f = (const float*)d_in[4];
    const float* w_ih_b = (const float*)d_in[5];
    // d_in[6] = w_hh_b — unused (backward cell starts from zero state)
    const float* b_ih_b = (const float*)d_in[7];
    const float* b_hh_b = (const float*)d_in[8];
    const float* w_fc   = (const float*)d_in[9];
    const float* b_fc   = (const float*)d_in[10];
    float* out = (float*)d_out;

    const int B = out_size;                 // 512
    const int T = in_sizes[0] / (B * 4);    // 1000

    bilstm_kernel<<<dim3(B), dim3(64), 0, stream>>>(
        x, w_ih_f, w_hh_f, b_ih_f, b_hh_f,
        w_ih_b, b_ih_b, b_hh_b, w_fc, b_fc, out, T);
}